// Round 9
// baseline (211.069 us; speedup 1.0000x reference)
//
#include <hip/hip_runtime.h>
#include <math.h>

#define NROWS 8192
#define NCOLS 1000
#define TPB   256
#define WPB   4                 // waves per block; each wave owns one row
#define NB    (NROWS / WPB)     // 2048 blocks
#define NSLOT 64
#define NEGF  -1.0e30f          // finite "-inf": exp(NEGF*0.05)==0 exactly, no inf*0 NaN

typedef float f32x4 __attribute__((ext_vector_type(4)));

// ws layout: [0,512) double S1[64] ; [512,1024) double S2[64] ; [1024,1280) unsigned MX[64]

__device__ __forceinline__ unsigned encf(float x) {
    unsigned u = __float_as_uint(x);
    return (u & 0x80000000u) ? ~u : (u | 0x80000000u);
}
__device__ __forceinline__ float decf(unsigned e) {
    unsigned u = (e & 0x80000000u) ? (e ^ 0x80000000u) : ~e;
    return __uint_as_float(u);
}
__device__ __forceinline__ float pick4(const float* a, int k) {
    return k == 0 ? a[0] : (k == 1 ? a[1] : (k == 2 ? a[2] : a[3]));
}

// Six 16B loads in ONE ordered asm block. "=&v" early-clobber: outputs must
// not alias the address inputs (loads write back asynchronously). "memory"
// clobber: no compiler VMEM may interleave, so vmcnt counting stays exact.
#define LOAD6(X0,X1,X2,X3,X4,X5, A0,A1,A2,A3,A4,A5)                    \
    asm volatile("global_load_dwordx4 %0, %6, off\n\t"                 \
                 "global_load_dwordx4 %1, %7, off\n\t"                 \
                 "global_load_dwordx4 %2, %8, off\n\t"                 \
                 "global_load_dwordx4 %3, %9, off\n\t"                 \
                 "global_load_dwordx4 %4, %10, off\n\t"                \
                 "global_load_dwordx4 %5, %11, off"                    \
                 : "=&v"(X0), "=&v"(X1), "=&v"(X2), "=&v"(X3), "=&v"(X4), "=&v"(X5) \
                 : "v"(A0), "v"(A1), "v"(A2), "v"(A3), "v"(A4), "v"(A5) \
                 : "memory")

// Counted wait + scheduling fence (rule #18: register-only consumers would
// otherwise be free to hoist above the asm waitcnt).
#define WAITVM(Nstr) do {                                              \
    asm volatile("s_waitcnt vmcnt(" Nstr ")" ::: "memory");            \
    __builtin_amdgcn_sched_barrier(0);                                 \
} while (0)

__device__ __forceinline__ void chunk_accum(
    f32x4 X0, f32x4 X1, f32x4 X2, f32x4 X3, f32x4 X4, f32x4 X5,
    int q, bool pad, int qt, int lt, int kt, int l,
    float (&m1)[6], float (&m2)[6], float (&zs)[6], float (&ds)[6],
    float &z1, float &z20, float (&sg)[7])
{
    float v[7][4];   // [0..4]=teachers, [5]=mimic, [6]=out_s
    #pragma unroll
    for (int k = 0; k < 4; ++k) {
        v[0][k] = X0[k]; v[1][k] = X1[k]; v[2][k] = X2[k];
        v[3][k] = X3[k]; v[4][k] = X4[k]; v[6][k] = X5[k];
    }
    if (pad) {
        #pragma unroll
        for (int s = 0; s < 7; ++s)
            #pragma unroll
            for (int k = 0; k < 4; ++k) v[s][k] = NEGF;
    }
    #pragma unroll
    for (int k = 0; k < 4; ++k)
        v[5][k] = (v[0][k] + v[1][k] + v[2][k] + v[3][k] + v[4][k]) * 0.2f;
    if (pad) {
        #pragma unroll
        for (int k = 0; k < 4; ++k) v[5][k] = NEGF;
    }

    #pragma unroll
    for (int s = 0; s < 6; ++s) {
        float a = v[s][0], b = v[s][1], c = v[s][2], d = v[s][3];
        float hi1 = fmaxf(a, b), lo1 = fminf(a, b);
        float hi2 = fmaxf(c, d), lo2 = fminf(c, d);
        float q1 = fmaxf(hi1, hi2);
        float q2 = fmaxf(fminf(hi1, hi2), fmaxf(lo1, lo2));
        float nm1 = fmaxf(m1[s], q1);
        float nm2 = fmaxf(fminf(m1[s], q1), fmaxf(m2[s], q2));
        m1[s] = nm1; m2[s] = nm2;
        float zz = 0.f, dot = 0.f;
        #pragma unroll
        for (int k = 0; k < 4; ++k) {
            float e = __expf(v[s][k] * 0.05f);   // e==0 exactly for padding
            zz += e; dot += e * v[6][k];
        }
        zs[s] += zz; ds[s] += dot;
    }
    #pragma unroll
    for (int k = 0; k < 4; ++k) {
        z1  += __expf(v[6][k]);
        z20 += __expf(v[6][k] * 0.05f);
    }
    // target-logit gather: the owning (q,lane) keeps its column's 7 values
    if (!pad && q == qt && l == lt) {
        #pragma unroll
        for (int s = 0; s < 7; ++s) sg[s] = pick4(v[s], kt);
    }
}

// 4 independent waves/block, one row per wave. No LDS, no barriers.
// 2-deep double-buffered asm load pipeline with counted vmcnt waits:
// X<-A, Y<-B, wait(6)|computeA, X<-C, wait(6)|computeB, Y<-D,
// wait(6)|computeC, wait(0)|computeD. 48 pinned payload VGPRs (vs R8's 96,
// which crashed: allocator reuse of pending-load regs under pressure).
__global__ __launch_bounds__(TPB, 3) void row_kernel(
    const float* __restrict__ p0, const float* __restrict__ p1,
    const float* __restrict__ p2, const float* __restrict__ p3,
    const float* __restrict__ p4, const float* __restrict__ p5,
    const int* __restrict__ targets,
    double* __restrict__ S1, double* __restrict__ S2, unsigned* __restrict__ MX)
{
    const int wave = threadIdx.x >> 6;
    const int l    = threadIdx.x & 63;
    const int row  = blockIdx.x * WPB + wave;
    const size_t rbase = (size_t)row * NCOLS;

    // Resolve the target index BEFORE the asm pipeline: the compiler's own
    // vmcnt wait for this load then drains only itself, keeping our counts
    // exact afterwards (our asm loads are the only VMEM ops in the pipeline).
    const int tgt = targets[row];
    const int t4  = tgt >> 2;
    const int lt  = t4 & 63;
    const int qt  = t4 >> 6;
    const int kt  = tgt & 3;
    __builtin_amdgcn_sched_barrier(0);

    // chunk offsets: q=0..2 fully valid (c4 = l+64q <= 191); q=3 valid iff
    // l<58 (c4<250); clamp tail address in-bounds, mask values after.
    int c4t = l + 192; if (c4t > 249) c4t = 249;
    const size_t off0 = rbase + ((size_t)l << 2);
    const size_t off1 = off0 + 256;          // (l+64)*4
    const size_t off2 = off0 + 512;          // (l+128)*4
    const size_t offT = rbase + ((size_t)c4t << 2);

    f32x4 X0,X1,X2,X3,X4,X5, Y0,Y1,Y2,Y3,Y4,Y5;
    LOAD6(X0,X1,X2,X3,X4,X5, p0+off0, p1+off0, p2+off0, p3+off0, p4+off0, p5+off0); // A
    LOAD6(Y0,Y1,Y2,Y3,Y4,Y5, p0+off1, p1+off1, p2+off1, p3+off1, p4+off1, p5+off1); // B

    float m1[6], m2[6], zs[6], ds[6];
    #pragma unroll
    for (int s = 0; s < 6; ++s) { m1[s] = NEGF; m2[s] = NEGF; zs[s] = 0.f; ds[s] = 0.f; }
    float z1 = 0.f, z20 = 0.f;
    float sg[7];
    #pragma unroll
    for (int s = 0; s < 7; ++s) sg[s] = 0.f;

    WAITVM("6");   // A landed (B in flight)
    chunk_accum(X0,X1,X2,X3,X4,X5, 0, false, qt,lt,kt,l, m1,m2,zs,ds, z1,z20, sg);
    LOAD6(X0,X1,X2,X3,X4,X5, p0+off2, p1+off2, p2+off2, p3+off2, p4+off2, p5+off2); // C

    WAITVM("6");   // B landed (C in flight)
    chunk_accum(Y0,Y1,Y2,Y3,Y4,Y5, 1, false, qt,lt,kt,l, m1,m2,zs,ds, z1,z20, sg);
    LOAD6(Y0,Y1,Y2,Y3,Y4,Y5, p0+offT, p1+offT, p2+offT, p3+offT, p4+offT, p5+offT); // D

    WAITVM("6");   // C landed (D in flight)
    chunk_accum(X0,X1,X2,X3,X4,X5, 2, false, qt,lt,kt,l, m1,m2,zs,ds, z1,z20, sg);

    WAITVM("0");   // D landed
    chunk_accum(Y0,Y1,Y2,Y3,Y4,Y5, 3, (l >= 58), qt,lt,kt,l, m1,m2,zs,ds, z1,z20, sg);

    // single in-wave butterfly over 26 quantities; no barriers
    #pragma unroll
    for (int xm = 1; xm < 64; xm <<= 1) {
        #pragma unroll
        for (int s = 0; s < 6; ++s) {
            float o1 = __shfl_xor(m1[s], xm);
            float o2 = __shfl_xor(m2[s], xm);
            float nm1 = fmaxf(m1[s], o1);
            float nm2 = fmaxf(fminf(m1[s], o1), fmaxf(m2[s], o2));
            m1[s] = nm1; m2[s] = nm2;
            zs[s] += __shfl_xor(zs[s], xm);
            ds[s] += __shfl_xor(ds[s], xm);
        }
        z1  += __shfl_xor(z1, xm);
        z20 += __shfl_xor(z20, xm);
    }
    // broadcast target logits from owning lane
    float sgv[7];
    #pragma unroll
    for (int s = 0; s < 7; ++s) sgv[s] = __shfl(sg[s], lt);

    if (l == 0) {
        const float lse1  = logf(z1);
        const float lse20 = logf(z20);
        const float CE    = lse1 - sgv[6];

        float KD[6], mg[6];
        float mmax = 0.f;   // margins >= 0 always
        #pragma unroll
        for (int s = 0; s < 6; ++s) {
            KD[s] = 400.f * lse20 - 20.f * (ds[s] / zs[s]);
            mg[s] = (sgv[s] == m1[s]) ? (m1[s] - m2[s]) : 0.f;
            mmax  = fmaxf(mmax, mg[s]);
        }
        float es[6], se = 0.f;
        #pragma unroll
        for (int s = 0; s < 6; ++s) { es[s] = __expf((mg[s] - mmax) * 0.5f); se += es[s]; }

        double rS2 = 0.0;
        #pragma unroll
        for (int s = 0; s < 6; ++s)
            rS2 += (double)(es[s] / se) * (double)sgv[s] * (double)(KD[s] - CE);

        float tmax = fmaxf(fmaxf(fmaxf(m1[0], m1[1]), fmaxf(m1[2], m1[3])), m1[4]);
        atomicAdd(&S1[row & (NSLOT - 1)], (double)CE);
        atomicAdd(&S2[row & (NSLOT - 1)], rS2);
        atomicMax(&MX[row & (NSLOT - 1)], encf(tmax));
    }
}

__global__ void final_kernel(const double* __restrict__ S1, const double* __restrict__ S2,
                             const unsigned* __restrict__ MX, float* __restrict__ out)
{
    const int tid = threadIdx.x;  // 64 threads
    double s1 = S1[tid], s2 = S2[tid];
    unsigned m = MX[tid];
    #pragma unroll
    for (int k = 32; k >= 1; k >>= 1) {
        s1 += __shfl_xor(s1, k);
        s2 += __shfl_xor(s2, k);
        unsigned om = __shfl_xor(m, k);
        m = (om > m) ? om : m;
    }
    if (tid == 0) {
        double maxp = (double)decf(m);
        out[0] = (float)((s1 + (0.8 / maxp) * s2) / (double)NROWS);
    }
}

extern "C" void kernel_launch(void* const* d_in, const int* in_sizes, int n_in,
                              void* d_out, int out_size, void* d_ws, size_t ws_size,
                              hipStream_t stream)
{
    const float* t1 = (const float*)d_in[0];
    const float* t2 = (const float*)d_in[1];
    const float* t3 = (const float*)d_in[2];
    const float* t4 = (const float*)d_in[3];
    const float* t5 = (const float*)d_in[4];
    const float* os = (const float*)d_in[5];
    const int* targets = (const int*)d_in[6];

    double*   S1 = (double*)d_ws;
    double*   S2 = S1 + NSLOT;
    unsigned* MX = (unsigned*)(S2 + NSLOT);

    hipMemsetAsync(d_ws, 0, NSLOT * (8 + 8 + 4), stream);
    row_kernel<<<NB, TPB, 0, stream>>>(t1, t2, t3, t4, t5, os, targets, S1, S2, MX);
    final_kernel<<<1, 64, 0, stream>>>(S1, S2, MX, (float*)d_out);
}